// Round 10
// baseline (258.183 us; speedup 1.0000x reference)
//
#include <hip/hip_runtime.h>
#include <hip/hip_bf16.h>
#include <stdint.h>
#include <math.h>

#define CH 256

typedef __attribute__((ext_vector_type(8)))  short short8;
typedef __attribute__((ext_vector_type(16))) short short16;
typedef __attribute__((ext_vector_type(4)))  float f32x4;

#define GL2LDS16(g, l) __builtin_amdgcn_global_load_lds(                       \
    (const __attribute__((address_space(1))) void*)(g),                        \
    (__attribute__((address_space(3))) void*)(l), 16, 0, 0)

__device__ inline short f2bf(float f) {
    __hip_bfloat16 h = __float2bfloat16(f);
    short s;
    __builtin_memcpy(&s, &h, 2);
    return s;
}

__device__ inline float bf2f(short s) {
    unsigned u = ((unsigned)(unsigned short)s) << 16;
    float f;
    __builtin_memcpy(&f, &u, 4);
    return f;
}

__device__ inline float warp_sum64(float v) {
    v += __shfl_xor(v, 32, 64);
    v += __shfl_xor(v, 16, 64);
    v += __shfl_xor(v, 8, 64);
    v += __shfl_xor(v, 4, 64);
    v += __shfl_xor(v, 2, 64);
    v += __shfl_xor(v, 1, 64);
    return v;
}

__device__ inline float warp_max64(float v) {
    v = fmaxf(v, __shfl_xor(v, 32, 64));
    v = fmaxf(v, __shfl_xor(v, 16, 64));
    v = fmaxf(v, __shfl_xor(v, 8, 64));
    v = fmaxf(v, __shfl_xor(v, 4, 64));
    v = fmaxf(v, __shfl_xor(v, 2, 64));
    v = fmaxf(v, __shfl_xor(v, 1, 64));
    return v;
}

// ==================================================================== MEGA edge kernel
// Per 32-edge-row block: virtual-A -> GEMM1(K=768) -> GN+ReLU -> h2(LDS) ->
// GEMM2(K=256, +eattr res, write eout f32) -> eo(LDS) -> KV(K=256, 512 cols)
// -> kv_bf + vbar. Blocks with bid >= EB run Q = x_bf x Wqt instead.
// Wave layout: 2x2 (wm = row half of 32, wn = col half of 256). FN=8 frags.
struct MArgs {
    const short* xbf; const short* eabf; const int* rowi; const int* coli;
    const float* mu; const float* rs;
    const float* vg; const float* vbt;       // gn_e1 gamma/beta (768)
    const short* We1t; const float* be1;
    const float* g2; const float* b2;        // gn_e2 gamma/beta (256)
    const short* We2t; const float* be2;
    const float* eattr; float* eout;
    const short* Wkvt; const float* bkv; short* kvbf; float* vbar;
    int E, EB;
    const short* Wqt; const float* bq; short* qbf; int N;
};

__global__ __launch_bounds__(256) void mega_edge(MArgs a)
{
    __shared__ short Bs[256 * 64];    // 32 KB streamed B chunk (XOR swizzle)
    __shared__ short As[32 * 72];     // virtual-A chunk (padded) / Q-A chunk
    __shared__ short hs[32 * 264];    // h2 tile, then eo tile (aliased)
    __shared__ int sidx[64];

    const int t = threadIdx.x;
    const int wave = t >> 6, lane = t & 63;
    const int q = lane >> 4, l16 = lane & 15;
    const int wm = wave & 1, wn = wave >> 1;
    const int bid = blockIdx.x;

    // stage 256x64 B chunk from Bt (row stride Kb), cols colbase..+256
    auto stageB = [&](const short* Bt, int colbase, int Kb, int k0) {
        #pragma unroll
        for (int p = 0; p < 8; p++) {
            int chunk = p * 256 + t;
            int r = chunk >> 3;
            int cs = ((chunk & 7) ^ (r & 7)) * 8;
            const short* gsrc = Bt + (size_t)(colbase + r) * Kb + k0 + cs;
            short* ldst = &Bs[(p * 256 + wave * 64) * 8];
            GL2LDS16(gsrc, ldst);
        }
    };
    // one 64-K MFMA step: A fragment from lds row-major (stride as), 8 B frags
    auto mmaStep = [&](const short* Ab, int as, int koff, f32x4* acc) {
        #pragma unroll
        for (int ks = 0; ks < 2; ks++) {
            short8 af = *(const short8*)&Ab[(wm * 16 + l16) * as + koff + ks * 32 + q * 8];
            #pragma unroll
            for (int ni = 0; ni < 8; ni++) {
                int R = wn * 128 + ni * 16 + l16;
                int slot = ((ks * 4 + q) ^ (R & 7)) * 8;
                short8 bf = *(const short8*)&Bs[R * 64 + slot];
                acc[ni] = __builtin_amdgcn_mfma_f32_16x16x32_bf16(af, bf, acc[ni], 0, 0, 0);
            }
        }
    };

    f32x4 acc[8];

    // ---------------- Q role ----------------
    if (bid >= a.EB) {
        int row0 = (bid - a.EB) * 32;
        #pragma unroll
        for (int i = 0; i < 8; i++) acc[i] = (f32x4){0.f, 0.f, 0.f, 0.f};
        for (int k0 = 0; k0 < 256; k0 += 64) {
            {   // stage A 32x64 from x_bf (1 pass, XOR swizzle, unpadded stride 64)
                int r = t >> 3;
                int cs = ((t & 7) ^ (r & 7)) * 8;
                int gr = row0 + r; if (gr >= a.N) gr = a.N - 1;
                const short* gsrc = a.xbf + (size_t)gr * CH + k0 + cs;
                short* ldst = &As[(wave * 64) * 8];
                GL2LDS16(gsrc, ldst);
            }
            stageB(a.Wqt, 0, 256, k0);
            __syncthreads();
            #pragma unroll
            for (int ks = 0; ks < 2; ks++) {
                int R = wm * 16 + l16;
                int slot = ((ks * 4 + q) ^ (R & 7)) * 8;
                short8 af = *(const short8*)&As[R * 64 + slot];
                #pragma unroll
                for (int ni = 0; ni < 8; ni++) {
                    int Rb = wn * 128 + ni * 16 + l16;
                    int sb = ((ks * 4 + q) ^ (Rb & 7)) * 8;
                    short8 bf = *(const short8*)&Bs[Rb * 64 + sb];
                    acc[ni] = __builtin_amdgcn_mfma_f32_16x16x32_bf16(af, bf, acc[ni], 0, 0, 0);
                }
            }
            __syncthreads();
        }
        #pragma unroll
        for (int ni = 0; ni < 8; ni++) {
            int cg = wn * 128 + ni * 16 + l16;
            float bv = a.bq[cg];
            #pragma unroll
            for (int r = 0; r < 4; r++) {
                int rg = row0 + wm * 16 + q * 4 + r;
                if (rg < a.N) a.qbf[(size_t)rg * CH + cg] = f2bf(acc[ni][r] + bv);
            }
        }
        return;
    }

    // ---------------- edge role ----------------
    int row0 = bid * 32;
    if (t < 32) { sidx[t] = a.rowi[row0 + t]; sidx[32 + t] = a.coli[row0 + t]; }
    __syncthreads();

    // ---- phase 1: GEMM1, K=768, virtual A ----
    #pragma unroll
    for (int i = 0; i < 8; i++) acc[i] = (f32x4){0.f, 0.f, 0.f, 0.f};
    for (int k0 = 0; k0 < 768; k0 += 64) {
        {   // build virtual A chunk 32x64
            int reg = k0 >> 8;
            int rloc = t >> 3;
            int c8 = (t & 7) * 8;
            int pos = k0 + c8;
            int G = pos / 24;
            float4 ga  = *(const float4*)&a.vg[pos];
            float4 ga2 = *(const float4*)&a.vg[pos + 4];
            float4 gb  = *(const float4*)&a.vbt[pos];
            float4 gb2 = *(const float4*)&a.vbt[pos + 4];
            int off = pos & 255;
            int e = row0 + rloc;
            const short* srow;
            if (reg == 0)      srow = a.xbf + (size_t)sidx[rloc] * CH;
            else if (reg == 1) srow = a.xbf + (size_t)sidx[32 + rloc] * CH;
            else               srow = a.eabf + (size_t)e * CH;
            short8 v8 = *(const short8*)&srow[off];
            float mm = a.mu[(size_t)e * 32 + G];
            float rr = a.rs[(size_t)e * 32 + G];
            short8 o;
            o[0] = f2bf(fmaxf((bf2f(v8[0]) - mm) * rr * ga.x + gb.x, 0.f));
            o[1] = f2bf(fmaxf((bf2f(v8[1]) - mm) * rr * ga.y + gb.y, 0.f));
            o[2] = f2bf(fmaxf((bf2f(v8[2]) - mm) * rr * ga.z + gb.z, 0.f));
            o[3] = f2bf(fmaxf((bf2f(v8[3]) - mm) * rr * ga.w + gb.w, 0.f));
            o[4] = f2bf(fmaxf((bf2f(v8[4]) - mm) * rr * ga2.x + gb2.x, 0.f));
            o[5] = f2bf(fmaxf((bf2f(v8[5]) - mm) * rr * ga2.y + gb2.y, 0.f));
            o[6] = f2bf(fmaxf((bf2f(v8[6]) - mm) * rr * ga2.z + gb2.z, 0.f));
            o[7] = f2bf(fmaxf((bf2f(v8[7]) - mm) * rr * ga2.w + gb2.w, 0.f));
            *(short8*)&As[rloc * 72 + c8] = o;
        }
        stageB(a.We1t, 0, 768, k0);
        __syncthreads();
        mmaStep(As, 72, 0, acc);
        __syncthreads();
    }
    // GN(gn_e2, groups of 8 cols)+ReLU -> h2 tile in LDS
    #pragma unroll
    for (int ni = 0; ni < 8; ni++) {
        int cg = wn * 128 + ni * 16 + l16;
        float bv = a.be1[cg];
        float ga = a.g2[cg], be = a.b2[cg];
        #pragma unroll
        for (int r = 0; r < 4; r++) {
            float v = acc[ni][r] + bv;
            float s = v, sq = v * v;
            s += __shfl_xor(s, 1, 64);  sq += __shfl_xor(sq, 1, 64);
            s += __shfl_xor(s, 2, 64);  sq += __shfl_xor(sq, 2, 64);
            s += __shfl_xor(s, 4, 64);  sq += __shfl_xor(sq, 4, 64);
            float mean = s * 0.125f;
            float var = sq * 0.125f - mean * mean;
            float o = fmaxf((v - mean) * rsqrtf(var + 1e-5f) * ga + be, 0.f);
            int rl = wm * 16 + q * 4 + r;
            hs[rl * 264 + cg] = f2bf(o);
        }
    }
    __syncthreads();

    // ---- phase 2: GEMM2 (h2 x We2t), +eattr residual -> eout + eo(LDS) ----
    #pragma unroll
    for (int i = 0; i < 8; i++) acc[i] = (f32x4){0.f, 0.f, 0.f, 0.f};
    for (int k0 = 0; k0 < 256; k0 += 64) {
        stageB(a.We2t, 0, 256, k0);
        __syncthreads();
        mmaStep(hs, 264, k0, acc);
        __syncthreads();
    }
    #pragma unroll
    for (int ni = 0; ni < 8; ni++) {
        int cg = wn * 128 + ni * 16 + l16;
        float bv = a.be2[cg];
        #pragma unroll
        for (int r = 0; r < 4; r++) {
            int rl = wm * 16 + q * 4 + r;
            int rg = row0 + rl;
            float v = acc[ni][r] + bv + a.eattr[(size_t)rg * CH + cg];
            a.eout[(size_t)rg * CH + cg] = v;
            hs[rl * 264 + cg] = f2bf(v);     // eo tile (aliases dead h2)
        }
    }
    __syncthreads();

    // ---- phase 3: KV (eo x Wkvt), 512 cols in two halves; vbar on V half ----
    #pragma unroll
    for (int half = 0; half < 2; half++) {
        #pragma unroll
        for (int i = 0; i < 8; i++) acc[i] = (f32x4){0.f, 0.f, 0.f, 0.f};
        for (int k0 = 0; k0 < 256; k0 += 64) {
            stageB(a.Wkvt, half * 256, 256, k0);
            __syncthreads();
            mmaStep(hs, 264, k0, acc);
            __syncthreads();
        }
        #pragma unroll
        for (int ni = 0; ni < 8; ni++) {
            int cg = wn * 128 + ni * 16 + l16;
            float bv = a.bkv[half * 256 + cg];
            float part = 0.f;
            #pragma unroll
            for (int r = 0; r < 4; r++) {
                int rg = row0 + wm * 16 + q * 4 + r;
                float v = acc[ni][r] + bv;
                a.kvbf[(size_t)rg * 512 + half * 256 + cg] = f2bf(v);
                part += v;
            }
            if (half == 1) {
                part += __shfl_xor(part, 16, 64);
                part += __shfl_xor(part, 32, 64);
                if (q == 0) atomicAdd(&a.vbar[cg], part);
            }
        }
    }
}

// ==================================================================== node GEMM (generic)
struct GArgs {
    const short* A; const short* Bt; const float* bias; const float* res;
    float* C; short* Cbf;
    const float* gamma; const float* beta;
    int M, K, Nc, ldc, coff;
};

template <int BM, int BN, int EPI>
__global__ __launch_bounds__(256) void mfma_gemm(GArgs g)
{
    constexpr int BK = 64;
    constexpr int HM = BM / 2, HN = BN / 2;
    constexpr int FM = HM / 16, FN = HN / 16;
    constexpr int PA = BM / 32;
    constexpr int PB = BN / 32;
    __shared__ short As[BM * BK];
    __shared__ short Bs[BN * BK];

    const int t = threadIdx.x;
    const int wave = t >> 6, lane = t & 63;
    const int q = lane >> 4, l16 = lane & 15;
    const int row0 = blockIdx.y * BM;
    const int col0 = blockIdx.x * BN;
    const int wm = wave & 1, wn = wave >> 1;

    f32x4 acc[FM][FN];
    #pragma unroll
    for (int i = 0; i < FM; i++)
        #pragma unroll
        for (int j = 0; j < FN; j++) acc[i][j] = (f32x4){0.f, 0.f, 0.f, 0.f};

    for (int k0 = 0; k0 < g.K; k0 += BK) {
        #pragma unroll
        for (int p = 0; p < PA; p++) {
            int chunk = p * 256 + t;
            int r = chunk >> 3;
            int cs = (((chunk & 7) ^ (r & 7)) * 8);
            int gr = row0 + r; if (gr >= g.M) gr = g.M - 1;
            const short* gsrc = g.A + (size_t)gr * g.K + k0 + cs;
            short* ldst = &As[(p * 256 + wave * 64) * 8];
            GL2LDS16(gsrc, ldst);
        }
        #pragma unroll
        for (int p = 0; p < PB; p++) {
            int chunk = p * 256 + t;
            int r = chunk >> 3;
            int cs = (((chunk & 7) ^ (r & 7)) * 8);
            const short* gsrc = g.Bt + (size_t)(col0 + r) * g.K + k0 + cs;
            short* ldst = &Bs[(p * 256 + wave * 64) * 8];
            GL2LDS16(gsrc, ldst);
        }
        __syncthreads();
        #pragma unroll
        for (int ks = 0; ks < 2; ks++) {
            short8 af[FM], bf[FN];
            #pragma unroll
            for (int mi = 0; mi < FM; mi++) {
                int R = wm * HM + mi * 16 + l16;
                int slot = ((ks * 4 + q) ^ (R & 7)) * 8;
                af[mi] = *(const short8*)&As[R * BK + slot];
            }
            #pragma unroll
            for (int ni = 0; ni < FN; ni++) {
                int R = wn * HN + ni * 16 + l16;
                int slot = ((ks * 4 + q) ^ (R & 7)) * 8;
                bf[ni] = *(const short8*)&Bs[R * BK + slot];
            }
            #pragma unroll
            for (int mi = 0; mi < FM; mi++)
                #pragma unroll
                for (int ni = 0; ni < FN; ni++)
                    acc[mi][ni] = __builtin_amdgcn_mfma_f32_16x16x32_bf16(
                        af[mi], bf[ni], acc[mi][ni], 0, 0, 0);
        }
        __syncthreads();
    }

    #pragma unroll
    for (int ni = 0; ni < FN; ni++) {
        int cg = col0 + wn * HN + ni * 16 + l16;
        float bv = g.bias[cg];
        if constexpr (EPI == 1) {
            float ga = g.gamma[cg], be = g.beta[cg];
            #pragma unroll
            for (int mi = 0; mi < FM; mi++) {
                #pragma unroll
                for (int r = 0; r < 4; r++) {
                    float v = acc[mi][ni][r] + bv;
                    float s = v, sq = v * v;
                    s += __shfl_xor(s, 1, 64);  sq += __shfl_xor(sq, 1, 64);
                    s += __shfl_xor(s, 2, 64);  sq += __shfl_xor(sq, 2, 64);
                    s += __shfl_xor(s, 4, 64);  sq += __shfl_xor(sq, 4, 64);
                    float mean = s * 0.125f;
                    float var = sq * 0.125f - mean * mean;
                    float o = fmaxf((v - mean) * rsqrtf(var + 1e-5f) * ga + be, 0.f);
                    int rg = row0 + wm * HM + mi * 16 + q * 4 + r;
                    if (rg < g.M) g.Cbf[(size_t)rg * g.ldc + g.coff + cg] = f2bf(o);
                }
            }
        } else {
            #pragma unroll
            for (int mi = 0; mi < FM; mi++) {
                #pragma unroll
                for (int r = 0; r < 4; r++) {
                    int rg = row0 + wm * HM + mi * 16 + q * 4 + r;
                    if (rg < g.M) {
                        float v = acc[mi][ni][r] + bv;
                        if (g.res) v += g.res[(size_t)rg * g.ldc + g.coff + cg];
                        if (g.C)   g.C[(size_t)rg * g.ldc + g.coff + cg] = v;
                        if (g.Cbf) g.Cbf[(size_t)rg * g.ldc + g.coff + cg] = f2bf(v);
                    }
                }
            }
        }
    }
}

// ==================================================================== merged prep
struct PrepPack {
    const float* wsrc[8];
    short* wdst[8];
    int wK[8];
    int wstart[8];
    int NW, NP;
    const float* x;
    short* x_bf;
    short* cat_bf;
    float2* xs;
    const float* gng;
    const float* gnb;
    float* vbar;
    const float* bk;
    const float* bv;
    float* bkv;
    int* counts;
    int N;
};

__global__ __launch_bounds__(256) void prep_kernel(PrepPack p)
{
    int bid = blockIdx.x;
    int t = threadIdx.x;
    if (bid < p.NW) {
        int m = 0;
        #pragma unroll
        for (int i = 1; i < 8; i++) if (bid >= p.wstart[i]) m = i;
        int k0 = (bid - p.wstart[m]) * 16;
        const float* src = p.wsrc[m];
        short16 o;
        #pragma unroll
        for (int j = 0; j < 16; j++) o[j] = f2bf(src[(size_t)(k0 + j) * 256 + t]);
        *(short16*)(p.wdst[m] + (size_t)t * p.wK[m] + k0) = o;
        return;
    }
    if (bid >= p.NW + p.NP) {
        int i = (bid - p.NW - p.NP) * 256 + t;
        if (i < p.N) p.counts[i] = 0;
        return;
    }
    int pb = bid - p.NW;
    if (pb == 0) {
        p.vbar[t] = 0.f;
        p.bkv[t] = p.bk[t];
        p.bkv[256 + t] = p.bv[t];
    }
    int r = pb * 8 + (t >> 5);
    int g = t & 31;
    if (r >= p.N) return;
    size_t xb = (size_t)r * CH + g * 8;
    float4 a = *(const float4*)&p.x[xb];
    float4 b = *(const float4*)&p.x[xb + 4];
    short8 xr;
    xr[0] = f2bf(a.x); xr[1] = f2bf(a.y); xr[2] = f2bf(a.z); xr[3] = f2bf(a.w);
    xr[4] = f2bf(b.x); xr[5] = f2bf(b.y); xr[6] = f2bf(b.z); xr[7] = f2bf(b.w);
    *(short8*)&p.x_bf[xb] = xr;
    float s  = a.x + a.y + a.z + a.w + b.x + b.y + b.z + b.w;
    float s2 = a.x*a.x + a.y*a.y + a.z*a.z + a.w*a.w
             + b.x*b.x + b.y*b.y + b.z*b.z + b.w*b.w;
    p.xs[(size_t)r * 32 + g] = make_float2(s, s2);
    float m = s * 0.125f;
    float var = s2 * 0.125f - m * m;
    float rsd = rsqrtf(var + 1e-5f);
    float4 g0 = *(const float4*)&p.gng[g * 8];
    float4 g1 = *(const float4*)&p.gng[g * 8 + 4];
    float4 b0 = *(const float4*)&p.gnb[g * 8];
    float4 b1 = *(const float4*)&p.gnb[g * 8 + 4];
    short8 o;
    o[0] = f2bf(fmaxf((a.x - m) * rsd * g0.x + b0.x, 0.f));
    o[1] = f2bf(fmaxf((a.y - m) * rsd * g0.y + b0.y, 0.f));
    o[2] = f2bf(fmaxf((a.z - m) * rsd * g0.z + b0.z, 0.f));
    o[3] = f2bf(fmaxf((a.w - m) * rsd * g0.w + b0.w, 0.f));
    o[4] = f2bf(fmaxf((b.x - m) * rsd * g1.x + b1.x, 0.f));
    o[5] = f2bf(fmaxf((b.y - m) * rsd * g1.y + b1.y, 0.f));
    o[6] = f2bf(fmaxf((b.z - m) * rsd * g1.z + b1.z, 0.f));
    o[7] = f2bf(fmaxf((b.w - m) * rsd * g1.w + b1.w, 0.f));
    *(short8*)&p.cat_bf[(size_t)r * (2 * CH) + g * 8] = o;
}

// ==================================================================== edge stats
__global__ __launch_bounds__(256) void estats_kernel(
    const float* __restrict__ eattr, const int* __restrict__ rowi,
    const int* __restrict__ coli, const float2* __restrict__ xs,
    float* __restrict__ mu, float* __restrict__ rs,
    short* __restrict__ eabf, int* __restrict__ counts, int E)
{
    __shared__ float2 ea[8][32];
    int t = threadIdx.x;
    int slot = t >> 5, g = t & 31;
    int e = blockIdx.x * 8 + slot;
    float4 a = *(const float4*)&eattr[(size_t)e * CH + g * 8];
    float4 b = *(const float4*)&eattr[(size_t)e * CH + g * 8 + 4];
    short8 o8;
    o8[0] = f2bf(a.x); o8[1] = f2bf(a.y); o8[2] = f2bf(a.z); o8[3] = f2bf(a.w);
    o8[4] = f2bf(b.x); o8[5] = f2bf(b.y); o8[6] = f2bf(b.z); o8[7] = f2bf(b.w);
    *(short8*)&eabf[(size_t)e * CH + g * 8] = o8;
    float s  = a.x + a.y + a.z + a.w + b.x + b.y + b.z + b.w;
    float s2 = a.x*a.x + a.y*a.y + a.z*a.z + a.w*a.w
             + b.x*b.x + b.y*b.y + b.z*b.z + b.w*b.w;
    ea[slot][g] = make_float2(s, s2);
    int r = rowi[e], c = coli[e];
    if (g == 0) atomicAdd(&counts[c], 1);
    __syncthreads();
    float S = 0.f, S2 = 0.f;
    #pragma unroll
    for (int j = 0; j < 3; j++) {
        int b3 = 3 * g + j;
        int src = b3 >> 5, idx = b3 & 31;
        float2 v;
        if (src == 0)      v = xs[(size_t)r * 32 + idx];
        else if (src == 1) v = xs[(size_t)c * 32 + idx];
        else               v = ea[slot][idx];
        S += v.x; S2 += v.y;
    }
    float m = S * (1.f / 24.f);
    float var = S2 * (1.f / 24.f) - m * m;
    mu[(size_t)e * 32 + g] = m;
    rs[(size_t)e * 32 + g] = rsqrtf(var + 1e-5f);
}

// ==================================================================== scan (1 block)
__global__ __launch_bounds__(1024) void scan_kernel(
    const int* __restrict__ counts, int* __restrict__ offsets,
    int* __restrict__ cursor, int N)
{
    __shared__ int s[1024];
    int t = threadIdx.x;
    int a = (2 * t     < N) ? counts[2 * t]     : 0;
    int b = (2 * t + 1 < N) ? counts[2 * t + 1] : 0;
    s[t] = a + b;
    __syncthreads();
    for (int off = 1; off < 1024; off <<= 1) {
        int v = (t >= off) ? s[t - off] : 0;
        __syncthreads();
        s[t] += v;
        __syncthreads();
    }
    int excl = (t > 0) ? s[t - 1] : 0;
    if (2 * t < N)     { offsets[2 * t]     = excl;     cursor[2 * t]     = excl; }
    if (2 * t + 1 < N) { offsets[2 * t + 1] = excl + a; cursor[2 * t + 1] = excl + a; }
    if (t == 1023) offsets[N] = s[1023];
}

// ==================================================================== edge scores + CSR fill
__global__ __launch_bounds__(256) void escore_kernel(
    const short* __restrict__ qb, const short* __restrict__ kvb,
    const int* __restrict__ coli, int* __restrict__ cursor,
    int* __restrict__ elist, float* __restrict__ sc, int E)
{
    int e = blockIdx.x * 4 + (threadIdx.x >> 6);
    int lane = threadIdx.x & 63;
    if (e >= E) return;
    int c = coli[e];
    if (lane == 0) { int p = atomicAdd(&cursor[c], 1); elist[p] = e; }
    const short* qrow = qb + (size_t)c * CH;
    const short* krow = kvb + (size_t)e * 512;
    float d0 = bf2f(qrow[lane])       * bf2f(krow[lane]);
    float d1 = bf2f(qrow[64 + lane])  * bf2f(krow[64 + lane]);
    float d2 = bf2f(qrow[128 + lane]) * bf2f(krow[128 + lane]);
    float d3 = bf2f(qrow[192 + lane]) * bf2f(krow[192 + lane]);
    d0 = warp_sum64(d0);
    d1 = warp_sum64(d1);
    d2 = warp_sum64(d2);
    d3 = warp_sum64(d3);
    if (lane == 0) {
        float4 o = {d0 * 0.125f, d1 * 0.125f, d2 * 0.125f, d3 * 0.125f};
        *(float4*)&sc[(size_t)e * 4] = o;
    }
}

// ==================================================================== segment softmax + PV
__global__ __launch_bounds__(256) void attn_kernel(
    const float* __restrict__ sc, const short* __restrict__ kvb,
    const int* __restrict__ offsets, const int* __restrict__ elist,
    const float* __restrict__ vbar, short* __restrict__ g_bf, int N, int E)
{
    int n = blockIdx.x;
    int h = threadIdx.x >> 6;
    int lane = threadIdx.x & 63;
    int s0 = offsets[n], s1 = offsets[n + 1];
    float out = 0.f;
    if (s1 > s0) {
        float m = -INFINITY, l = 0.f;
        for (int base = s0; base < s1; base += 64) {
            int cn = s1 - base; if (cn > 64) cn = 64;
            int e = (lane < cn) ? elist[base + lane] : 0;
            float s = (lane < cn) ? sc[(size_t)e * 4 + h] : -INFINITY;
            float mc = warp_max64(s);
            float nm = fmaxf(m, mc);
            float scale = __expf(m - nm);
            float pp = (lane < cn) ? __expf(s - nm) : 0.f;
            float ps = warp_sum64(pp);
            l = l * scale + ps;
            out *= scale;
            m = nm;
            for (int i = 0; i < cn; i++) {
                float pi = __shfl(pp, i, 64);
                int   ei = __shfl(e, i, 64);
                out += pi * bf2f(kvb[(size_t)ei * 512 + 256 + h * 64 + lane]);
            }
        }
        out /= l;
    } else {
        out = vbar[h * 64 + lane] * (1.f / (float)E);
    }
    g_bf[(size_t)n * CH + h * 64 + lane] = f2bf(out);
}

// ==================================================================== launch
extern "C" void kernel_launch(void* const* d_in, const int* in_sizes, int n_in,
                              void* d_out, int out_size, void* d_ws, size_t ws_size,
                              hipStream_t stream)
{
    const float* x       = (const float*)d_in[0];
    const int*   ei      = (const int*)d_in[1];
    const float* eattr   = (const float*)d_in[2];
    const float* gn_e1_g = (const float*)d_in[3];
    const float* gn_e1_b = (const float*)d_in[4];
    const float* We1     = (const float*)d_in[5];
    const float* be1     = (const float*)d_in[6];
    const float* gn_e2_g = (const float*)d_in[7];
    const float* gn_e2_b = (const float*)d_in[8];
    const float* We2     = (const float*)d_in[9];
    const float* be2     = (const float*)d_in[10];
    const float* gn_n_g  = (const float*)d_in[11];
    const float* gn_n_b  = (const float*)d_in[12];
    const float* Wq      = (const float*)d_in[13];
    const float* bq      = (const float*)d_in[14];
    const float* Wk      = (const float*)d_in[15];
    const float* bk      = (const float*)d_in[16];
    const float* Wv      = (const float*)d_in[17];
    const float* bv      = (const float*)d_in[18];
    const float* Wo      = (const float*)d_in[19];
    const float* bo      = (const float*)d_in[20];
    const float* Wn1     = (const float*)d_in[21];
    const float* bn1     = (const float*)d_in[22];
    const float* gn_n2_g = (const float*)d_in[23];
    const float* gn_n2_b = (const float*)d_in[24];
    const float* Wn2     = (const float*)d_in[25];
    const float* bn2     = (const float*)d_in[26];

    const int N = in_sizes[0] / CH;
    const int E = in_sizes[2] / CH;

    float* nout = (float*)d_out;
    float* eout = (float*)d_out + (size_t)N * CH;

    // ---- workspace ----
    char* base = (char*)d_ws;
    short* kv_bf  = (short*)base; base += (size_t)E * 512 * 2;
    short* eabf   = (short*)base; base += (size_t)E * CH * 2;
    short* q_bf   = (short*)base; base += (size_t)N * CH * 2;
    short* g_bf   = (short*)base; base += (size_t)N * CH * 2;
    short* cat_bf = (short*)base; base += (size_t)N * 2 * CH * 2;
    short* hn_bf  = (short*)base; base += (size_t)N * CH * 2;
    short* x_bf   = (short*)base; base += (size_t)N * CH * 2;
    float2* xs    = (float2*)base; base += (size_t)N * 32 * 8;
    float* mub    = (float*)base; base += (size_t)E * 32 * 4;
    float* rsb    = (float*)base; base += (size_t)E * 32 * 4;
    float* sc     = (float*)base; base += (size_t)E * 4 * 4;
    float* vbar   = (float*)base; base += 1024;
    float* bkv    = (float*)base; base += 2048;
    short* We1t = (short*)base; base += (size_t)768 * 256 * 2;
    short* We2t = (short*)base; base += (size_t)256 * 256 * 2;
    short* Wqt  = (short*)base; base += (size_t)256 * 256 * 2;
    short* Wkvt = (short*)base; base += (size_t)512 * 256 * 2;
    short* Wot  = (short*)base; base += (size_t)256 * 256 * 2;
    short* Wn1t = (short*)base; base += (size_t)512 * 256 * 2;
    short* Wn2t = (short*)base; base += (size_t)256 * 256 * 2;
    int* counts  = (int*)base;
    int* offsets = counts + N;
    int* cursor  = offsets + (N + 1) + 3;
    int* elist   = cursor + N;

    const int* rowi = ei;
    const int* coli = ei + E;

    dim3 blk(256);

    // ---- merged prep ----
    PrepPack pp;
    const float* wsrc[8] = {We1, We2, Wq, Wk, Wv, Wo, Wn1, Wn2};
    short* wdst[8] = {We1t, We2t, Wqt, Wkvt, Wkvt + (size_t)256 * 256, Wot, Wn1t, Wn2t};
    const int wKd[8] = {768, 256, 256, 256, 256, 256, 512, 256};
    int acc = 0;
    for (int i = 0; i < 8; i++) {
        pp.wsrc[i] = wsrc[i]; pp.wdst[i] = wdst[i]; pp.wK[i] = wKd[i];
        pp.wstart[i] = acc; acc += wKd[i] / 16;
    }
    pp.NW = acc;
    pp.NP = (N + 7) / 8;
    pp.x = x; pp.x_bf = x_bf; pp.cat_bf = cat_bf; pp.xs = xs;
    pp.gng = gn_n_g; pp.gnb = gn_n_b;
    pp.vbar = vbar; pp.bk = bk; pp.bv = bv; pp.bkv = bkv;
    pp.counts = counts; pp.N = N;
    int nzero = (N + 255) / 256;
    prep_kernel<<<pp.NW + pp.NP + nzero, blk, 0, stream>>>(pp);

    estats_kernel<<<E / 8, blk, 0, stream>>>(eattr, rowi, coli, xs, mub, rsb,
                                             eabf, counts, E);
    scan_kernel<<<1, 1024, 0, stream>>>(counts, offsets, cursor, N);

    // ---- MEGA edge (GEMM1 -> GN -> GEMM2 -> KV) + Q dual ----
    MArgs ma;
    ma.xbf = x_bf; ma.eabf = eabf; ma.rowi = rowi; ma.coli = coli;
    ma.mu = mub; ma.rs = rsb;
    ma.vg = gn_e1_g; ma.vbt = gn_e1_b;
    ma.We1t = We1t; ma.be1 = be1;
    ma.g2 = gn_e2_g; ma.b2 = gn_e2_b;
    ma.We2t = We2t; ma.be2 = be2;
    ma.eattr = eattr; ma.eout = eout;
    ma.Wkvt = Wkvt; ma.bkv = bkv; ma.kvbf = kv_bf; ma.vbar = vbar;
    ma.E = E; ma.EB = E / 32;
    ma.Wqt = Wqt; ma.bq = bq; ma.qbf = q_bf; ma.N = N;
    mega_edge<<<E / 32 + (N + 31) / 32, blk, 0, stream>>>(ma);

    // ---- attention ----
    escore_kernel<<<(E + 3) / 4, blk, 0, stream>>>(q_bf, kv_bf, coli, cursor, elist, sc, E);
    attn_kernel<<<N, blk, 0, stream>>>(sc, kv_bf, offsets, elist, vbar, g_bf, N, E);

    // ---- Wo -> cat right half (bf16) ----
    GArgs ga = {};
    ga.A = g_bf; ga.Bt = Wot; ga.bias = bo; ga.Cbf = cat_bf;
    ga.M = N; ga.K = CH; ga.Nc = CH; ga.ldc = 2 * CH; ga.coff = CH;
    mfma_gemm<32, 64, 0><<<dim3(4, (N + 31) / 32), blk, 0, stream>>>(ga);

    // ---- node MLP ----
    ga = {};
    ga.A = cat_bf; ga.Bt = Wn1t; ga.bias = bn1; ga.Cbf = hn_bf;
    ga.gamma = gn_n2_g; ga.beta = gn_n2_b;
    ga.M = N; ga.K = 2 * CH; ga.Nc = CH; ga.ldc = CH; ga.coff = 0;
    mfma_gemm<32, 64, 1><<<dim3(4, (N + 31) / 32), blk, 0, stream>>>(ga);

    ga = {};
    ga.A = hn_bf; ga.Bt = Wn2t; ga.bias = bn2; ga.res = x; ga.C = nout;
    ga.M = N; ga.K = CH; ga.Nc = CH; ga.ldc = CH; ga.coff = 0;
    mfma_gemm<32, 64, 0><<<dim3(4, (N + 31) / 32), blk, 0, stream>>>(ga);
}

// Round 11
// 237.953 us; speedup vs baseline: 1.0850x; 1.0850x over previous
//
#include <hip/hip_runtime.h>
#include <hip/hip_bf16.h>
#include <stdint.h>
#include <math.h>

#define CH 256

typedef __attribute__((ext_vector_type(8)))  short short8;
typedef __attribute__((ext_vector_type(16))) short short16;
typedef __attribute__((ext_vector_type(4)))  float f32x4;

#define GL2LDS16(g, l) __builtin_amdgcn_global_load_lds(                       \
    (const __attribute__((address_space(1))) void*)(g),                        \
    (__attribute__((address_space(3))) void*)(l), 16, 0, 0)

__device__ inline short f2bf(float f) {
    __hip_bfloat16 h = __float2bfloat16(f);
    short s;
    __builtin_memcpy(&s, &h, 2);
    return s;
}

__device__ inline float bf2f(short s) {
    unsigned u = ((unsigned)(unsigned short)s) << 16;
    float f;
    __builtin_memcpy(&f, &u, 4);
    return f;
}

__device__ inline float warp_sum64(float v) {
    v += __shfl_xor(v, 32, 64);
    v += __shfl_xor(v, 16, 64);
    v += __shfl_xor(v, 8, 64);
    v += __shfl_xor(v, 4, 64);
    v += __shfl_xor(v, 2, 64);
    v += __shfl_xor(v, 1, 64);
    return v;
}

__device__ inline float warp_max64(float v) {
    v = fmaxf(v, __shfl_xor(v, 32, 64));
    v = fmaxf(v, __shfl_xor(v, 16, 64));
    v = fmaxf(v, __shfl_xor(v, 8, 64));
    v = fmaxf(v, __shfl_xor(v, 4, 64));
    v = fmaxf(v, __shfl_xor(v, 2, 64));
    v = fmaxf(v, __shfl_xor(v, 1, 64));
    return v;
}

// ==================================================================== MFMA GEMM
// BMxBN tile, BK=64, 2x2 wave grid, 16x16x32 bf16 MFMA. (R8-best geometry)
// AMODE 0: A staged via global_load_lds with XOR bank swizzle.
// AMODE 1: A built virtually = bf16(relu(gn_g24(cat(xbf[row],xbf[col],eabf)))).
// EPI 1: GroupNorm(8 cols)+ReLU -> bf16 Cbf only. EPI 0: f32 C/res/bf16 Cbf.
// DUAL : blocks with by >= y_split run the Q GEMM (A2/Bt2/bias2/Cbf2).
// VB   : column sums of cols>=256 atomically into vbar (KV path).
// FILL : edge-role blocks with bx==0 scatter their rows into elist via cursor.
struct GArgs {
    const short* A; const short* Bt; const float* bias; const float* res;
    float* C; short* Cbf;
    const float* gamma; const float* beta; float* vbar;
    int M, K, Nc, ldc, coff;
    const short* A2; const short* Bt2; const float* bias2; short* Cbf2;
    int M2, Nc2, y_split;
    const short* xbf; const short* eabf; const int* rowi; const int* coli;
    const float* mu; const float* rs; const float* vg; const float* vbt;
    int* cursor; int* elist;
};

template <int BM, int BN, int AMODE, int EPI, int DUAL, int VB, int FILL>
__global__ __launch_bounds__(256) void mfma_gemm(GArgs g)
{
    constexpr int BK = 64;
    constexpr int AK = AMODE ? (BK + 8) : BK;
    constexpr int HM = BM / 2, HN = BN / 2;
    constexpr int FM = HM / 16, FN = HN / 16;
    constexpr int PA = BM / 32;
    constexpr int PB = BN / 32;
    __shared__ short As[BM * AK];
    __shared__ short Bs[BN * BK];
    __shared__ int sidx[AMODE ? 2 * BM : 1];

    const short* A = g.A; const short* Bt = g.Bt;
    const float* bias = g.bias; const float* res = g.res;
    float* C = g.C; short* Cbf = g.Cbf;
    int M = g.M, ldc = g.ldc, co = g.coff;
    const int K = g.K;
    int by = blockIdx.y, bx = blockIdx.x;
    bool qrole = false;
    if constexpr (DUAL) {
        if (by >= g.y_split) {
            by -= g.y_split;
            if (bx * BN >= g.Nc2) return;
            qrole = true;
            A = g.A2; Bt = g.Bt2; bias = g.bias2; Cbf = g.Cbf2;
            C = nullptr; res = nullptr;
            M = g.M2; ldc = g.Nc2; co = 0;
        }
    }

    const int t = threadIdx.x;
    const int wave = t >> 6, lane = t & 63;
    const int q = lane >> 4, l16 = lane & 15;
    const int row0 = by * BM;
    const int col0 = bx * BN;
    const int wm = wave & 1, wn = wave >> 1;

    if constexpr (AMODE) {
        if (t < BM) {
            int gr = row0 + t; if (gr >= M) gr = M - 1;
            sidx[t] = g.rowi[gr];
            sidx[BM + t] = g.coli[gr];
        }
        __syncthreads();
    }

    if constexpr (FILL) {
        if (!qrole && bx == 0 && t < BM) {
            int rg = row0 + t;
            if (rg < M) {
                int c = g.coli[rg];
                int p = atomicAdd(&g.cursor[c], 1);
                g.elist[p] = rg;
            }
        }
    }

    f32x4 acc[FM][FN];
    #pragma unroll
    for (int i = 0; i < FM; i++)
        #pragma unroll
        for (int j = 0; j < FN; j++) acc[i][j] = (f32x4){0.f, 0.f, 0.f, 0.f};

    for (int k0 = 0; k0 < K; k0 += BK) {
        if constexpr (AMODE == 1) {
            int reg = k0 >> 8;                 // 0=x[row],1=x[col],2=eattr
            int rloc = t >> 3;
            int c8 = (t & 7) * 8;
            int pos = k0 + c8;
            int G = pos / 24;                  // 8-chunks never cross a group of 24
            float4 ga  = *(const float4*)&g.vg[pos];
            float4 ga2 = *(const float4*)&g.vg[pos + 4];
            float4 gb  = *(const float4*)&g.vbt[pos];
            float4 gb2 = *(const float4*)&g.vbt[pos + 4];
            int off = pos & 255;
            #pragma unroll
            for (int p = 0; p < BM / 32; p++) {
                int r2 = p * 32 + rloc;
                int e = row0 + r2; if (e >= M) e = M - 1;
                const short* srow;
                if (reg == 0)      srow = g.xbf + (size_t)sidx[r2] * CH;
                else if (reg == 1) srow = g.xbf + (size_t)sidx[BM + r2] * CH;
                else               srow = g.eabf + (size_t)e * CH;
                short8 v8 = *(const short8*)&srow[off];
                float mm = g.mu[(size_t)e * 32 + G];
                float rr = g.rs[(size_t)e * 32 + G];
                short8 o;
                o[0] = f2bf(fmaxf((bf2f(v8[0]) - mm) * rr * ga.x + gb.x, 0.f));
                o[1] = f2bf(fmaxf((bf2f(v8[1]) - mm) * rr * ga.y + gb.y, 0.f));
                o[2] = f2bf(fmaxf((bf2f(v8[2]) - mm) * rr * ga.z + gb.z, 0.f));
                o[3] = f2bf(fmaxf((bf2f(v8[3]) - mm) * rr * ga.w + gb.w, 0.f));
                o[4] = f2bf(fmaxf((bf2f(v8[4]) - mm) * rr * ga2.x + gb2.x, 0.f));
                o[5] = f2bf(fmaxf((bf2f(v8[5]) - mm) * rr * ga2.y + gb2.y, 0.f));
                o[6] = f2bf(fmaxf((bf2f(v8[6]) - mm) * rr * ga2.z + gb2.z, 0.f));
                o[7] = f2bf(fmaxf((bf2f(v8[7]) - mm) * rr * ga2.w + gb2.w, 0.f));
                *(short8*)&As[r2 * AK + c8] = o;
            }
        } else {
            #pragma unroll
            for (int p = 0; p < PA; p++) {
                int chunk = p * 256 + t;
                int r = chunk >> 3;
                int cs = (((chunk & 7) ^ (r & 7)) * 8);   // XOR bank swizzle
                int gr = row0 + r; if (gr >= M) gr = M - 1;
                const short* gsrc = A + (size_t)gr * K + k0 + cs;
                short* ldst = &As[(p * 256 + wave * 64) * 8];
                GL2LDS16(gsrc, ldst);
            }
        }
        #pragma unroll
        for (int p = 0; p < PB; p++) {
            int chunk = p * 256 + t;
            int r = chunk >> 3;
            int cs = (((chunk & 7) ^ (r & 7)) * 8);
            const short* gsrc = Bt + (size_t)(col0 + r) * K + k0 + cs;
            short* ldst = &Bs[(p * 256 + wave * 64) * 8];
            GL2LDS16(gsrc, ldst);
        }
        __syncthreads();
        #pragma unroll
        for (int ks = 0; ks < 2; ks++) {
            short8 af[FM], bf[FN];
            #pragma unroll
            for (int mi = 0; mi < FM; mi++) {
                int R = wm * HM + mi * 16 + l16;
                if constexpr (AMODE == 1)
                    af[mi] = *(const short8*)&As[R * AK + ks * 32 + q * 8];
                else {
                    int slot = ((ks * 4 + q) ^ (R & 7)) * 8;
                    af[mi] = *(const short8*)&As[R * BK + slot];
                }
            }
            #pragma unroll
            for (int ni = 0; ni < FN; ni++) {
                int R = wn * HN + ni * 16 + l16;
                int slot = ((ks * 4 + q) ^ (R & 7)) * 8;
                bf[ni] = *(const short8*)&Bs[R * BK + slot];
            }
            #pragma unroll
            for (int mi = 0; mi < FM; mi++)
                #pragma unroll
                for (int ni = 0; ni < FN; ni++)
                    acc[mi][ni] = __builtin_amdgcn_mfma_f32_16x16x32_bf16(
                        af[mi], bf[ni], acc[mi][ni], 0, 0, 0);
        }
        __syncthreads();
    }

    // ---- epilogue; C/D layout: col = l16, row = q*4 + r ----
    #pragma unroll
    for (int ni = 0; ni < FN; ni++) {
        int cg = col0 + wn * HN + ni * 16 + l16;
        float bv = bias[cg];
        if constexpr (EPI == 1) {
            float ga = g.gamma[cg], be = g.beta[cg];
            #pragma unroll
            for (int mi = 0; mi < FM; mi++) {
                #pragma unroll
                for (int r = 0; r < 4; r++) {
                    float v = acc[mi][ni][r] + bv;
                    float s = v, sq = v * v;
                    s += __shfl_xor(s, 1, 64);  sq += __shfl_xor(sq, 1, 64);
                    s += __shfl_xor(s, 2, 64);  sq += __shfl_xor(sq, 2, 64);
                    s += __shfl_xor(s, 4, 64);  sq += __shfl_xor(sq, 4, 64);
                    float mean = s * 0.125f;
                    float var = sq * 0.125f - mean * mean;
                    float o = fmaxf((v - mean) * rsqrtf(var + 1e-5f) * ga + be, 0.f);
                    int rg = row0 + wm * HM + mi * 16 + q * 4 + r;
                    if (rg < M) Cbf[(size_t)rg * ldc + co + cg] = f2bf(o);
                }
            }
        } else {
            #pragma unroll
            for (int mi = 0; mi < FM; mi++) {
                #pragma unroll
                for (int r = 0; r < 4; r++) {
                    int rg = row0 + wm * HM + mi * 16 + q * 4 + r;
                    if (rg < M) {
                        float v = acc[mi][ni][r] + bv;
                        if (res) v += res[(size_t)rg * ldc + co + cg];
                        if (C)   C[(size_t)rg * ldc + co + cg] = v;
                        if (Cbf) Cbf[(size_t)rg * ldc + co + cg] = f2bf(v);
                    }
                }
            }
            if constexpr (VB) {
                if (!qrole && cg >= 256) {
                    float part = 0.f;
                    #pragma unroll
                    for (int mi = 0; mi < FM; mi++)
                        #pragma unroll
                        for (int r = 0; r < 4; r++) {
                            int rg = row0 + wm * HM + mi * 16 + q * 4 + r;
                            if (rg < M) part += acc[mi][ni][r] + bv;
                        }
                    part += __shfl_xor(part, 16, 64);
                    part += __shfl_xor(part, 32, 64);
                    if (q == 0) atomicAdd(&g.vbar[cg - 256], part);
                }
            }
        }
    }
}

// ==================================================================== merged prep
struct PrepPack {
    const float* wsrc[8];
    short* wdst[8];
    int wK[8];
    int wstart[8];
    int NW, NP;
    const float* x;
    short* x_bf;
    short* cat_bf;
    float2* xs;
    const float* gng;
    const float* gnb;
    float* vbar;
    const float* bk;
    const float* bv;
    float* bkv;
    int* counts;
    int N;
};

__global__ __launch_bounds__(256) void prep_kernel(PrepPack p)
{
    int bid = blockIdx.x;
    int t = threadIdx.x;
    if (bid < p.NW) {
        int m = 0;
        #pragma unroll
        for (int i = 1; i < 8; i++) if (bid >= p.wstart[i]) m = i;
        int k0 = (bid - p.wstart[m]) * 16;
        const float* src = p.wsrc[m];
        short16 o;
        #pragma unroll
        for (int j = 0; j < 16; j++) o[j] = f2bf(src[(size_t)(k0 + j) * 256 + t]);
        *(short16*)(p.wdst[m] + (size_t)t * p.wK[m] + k0) = o;
        return;
    }
    if (bid >= p.NW + p.NP) {
        int i = (bid - p.NW - p.NP) * 256 + t;
        if (i < p.N) p.counts[i] = 0;
        return;
    }
    int pb = bid - p.NW;
    if (pb == 0) {
        p.vbar[t] = 0.f;
        p.bkv[t] = p.bk[t];
        p.bkv[256 + t] = p.bv[t];
    }
    int r = pb * 8 + (t >> 5);
    int g = t & 31;
    if (r >= p.N) return;
    size_t xb = (size_t)r * CH + g * 8;
    float4 a = *(const float4*)&p.x[xb];
    float4 b = *(const float4*)&p.x[xb + 4];
    short8 xr;
    xr[0] = f2bf(a.x); xr[1] = f2bf(a.y); xr[2] = f2bf(a.z); xr[3] = f2bf(a.w);
    xr[4] = f2bf(b.x); xr[5] = f2bf(b.y); xr[6] = f2bf(b.z); xr[7] = f2bf(b.w);
    *(short8*)&p.x_bf[xb] = xr;
    float s  = a.x + a.y + a.z + a.w + b.x + b.y + b.z + b.w;
    float s2 = a.x*a.x + a.y*a.y + a.z*a.z + a.w*a.w
             + b.x*b.x + b.y*b.y + b.z*b.z + b.w*b.w;
    p.xs[(size_t)r * 32 + g] = make_float2(s, s2);
    float m = s * 0.125f;
    float var = s2 * 0.125f - m * m;
    float rsd = rsqrtf(var + 1e-5f);
    float4 g0 = *(const float4*)&p.gng[g * 8];
    float4 g1 = *(const float4*)&p.gng[g * 8 + 4];
    float4 b0 = *(const float4*)&p.gnb[g * 8];
    float4 b1 = *(const float4*)&p.gnb[g * 8 + 4];
    short8 o;
    o[0] = f2bf(fmaxf((a.x - m) * rsd * g0.x + b0.x, 0.f));
    o[1] = f2bf(fmaxf((a.y - m) * rsd * g0.y + b0.y, 0.f));
    o[2] = f2bf(fmaxf((a.z - m) * rsd * g0.z + b0.z, 0.f));
    o[3] = f2bf(fmaxf((a.w - m) * rsd * g0.w + b0.w, 0.f));
    o[4] = f2bf(fmaxf((b.x - m) * rsd * g1.x + b1.x, 0.f));
    o[5] = f2bf(fmaxf((b.y - m) * rsd * g1.y + b1.y, 0.f));
    o[6] = f2bf(fmaxf((b.z - m) * rsd * g1.z + b1.z, 0.f));
    o[7] = f2bf(fmaxf((b.w - m) * rsd * g1.w + b1.w, 0.f));
    *(short8*)&p.cat_bf[(size_t)r * (2 * CH) + g * 8] = o;
}

// ==================================================================== edge stats
__global__ __launch_bounds__(256) void estats_kernel(
    const float* __restrict__ eattr, const int* __restrict__ rowi,
    const int* __restrict__ coli, const float2* __restrict__ xs,
    float* __restrict__ mu, float* __restrict__ rs,
    short* __restrict__ eabf, int* __restrict__ counts, int E)
{
    __shared__ float2 ea[8][32];
    int t = threadIdx.x;
    int slot = t >> 5, g = t & 31;
    int e = blockIdx.x * 8 + slot;
    float4 a = *(const float4*)&eattr[(size_t)e * CH + g * 8];
    float4 b = *(const float4*)&eattr[(size_t)e * CH + g * 8 + 4];
    short8 o8;
    o8[0] = f2bf(a.x); o8[1] = f2bf(a.y); o8[2] = f2bf(a.z); o8[3] = f2bf(a.w);
    o8[4] = f2bf(b.x); o8[5] = f2bf(b.y); o8[6] = f2bf(b.z); o8[7] = f2bf(b.w);
    *(short8*)&eabf[(size_t)e * CH + g * 8] = o8;
    float s  = a.x + a.y + a.z + a.w + b.x + b.y + b.z + b.w;
    float s2 = a.x*a.x + a.y*a.y + a.z*a.z + a.w*a.w
             + b.x*b.x + b.y*b.y + b.z*b.z + b.w*b.w;
    ea[slot][g] = make_float2(s, s2);
    int r = rowi[e], c = coli[e];
    if (g == 0) atomicAdd(&counts[c], 1);
    __syncthreads();
    float S = 0.f, S2 = 0.f;
    #pragma unroll
    for (int j = 0; j < 3; j++) {
        int b3 = 3 * g + j;
        int src = b3 >> 5, idx = b3 & 31;
        float2 v;
        if (src == 0)      v = xs[(size_t)r * 32 + idx];
        else if (src == 1) v = xs[(size_t)c * 32 + idx];
        else               v = ea[slot][idx];
        S += v.x; S2 += v.y;
    }
    float m = S * (1.f / 24.f);
    float var = S2 * (1.f / 24.f) - m * m;
    mu[(size_t)e * 32 + g] = m;
    rs[(size_t)e * 32 + g] = rsqrtf(var + 1e-5f);
}

// ==================================================================== scan (1 block)
__global__ __launch_bounds__(1024) void scan_kernel(
    const int* __restrict__ counts, int* __restrict__ offsets,
    int* __restrict__ cursor, int N)
{
    __shared__ int s[1024];
    int t = threadIdx.x;
    int a = (2 * t     < N) ? counts[2 * t]     : 0;
    int b = (2 * t + 1 < N) ? counts[2 * t + 1] : 0;
    s[t] = a + b;
    __syncthreads();
    for (int off = 1; off < 1024; off <<= 1) {
        int v = (t >= off) ? s[t - off] : 0;
        __syncthreads();
        s[t] += v;
        __syncthreads();
    }
    int excl = (t > 0) ? s[t - 1] : 0;
    if (2 * t < N)     { offsets[2 * t]     = excl;     cursor[2 * t]     = excl; }
    if (2 * t + 1 < N) { offsets[2 * t + 1] = excl + a; cursor[2 * t + 1] = excl + a; }
    if (t == 1023) offsets[N] = s[1023];
}

// ==================================================================== attention
// block = node; fused scoring (all 4 waves cooperate) + per-wave (=head)
// online softmax + PV. Scores never touch global memory.
__global__ __launch_bounds__(256) void attn_kernel(
    const short* __restrict__ qb, const short* __restrict__ kvb,
    const int* __restrict__ offsets, const int* __restrict__ elist,
    const float* __restrict__ vbar, short* __restrict__ g_bf, int N, int E)
{
    __shared__ int eidx[64];
    __shared__ float scl[4 * 64];
    int n = blockIdx.x;
    int wave = threadIdx.x >> 6;
    int lane = threadIdx.x & 63;
    int s0 = offsets[n], s1 = offsets[n + 1];
    float q0 = bf2f(qb[(size_t)n * CH + lane]);
    float q1 = bf2f(qb[(size_t)n * CH + 64 + lane]);
    float q2 = bf2f(qb[(size_t)n * CH + 128 + lane]);
    float q3 = bf2f(qb[(size_t)n * CH + 192 + lane]);
    float out = 0.f, m = -INFINITY, l = 0.f;
    for (int base = s0; base < s1; base += 64) {
        int cn = s1 - base; if (cn > 64) cn = 64;
        if (wave == 0 && lane < cn) eidx[lane] = elist[base + lane];
        __syncthreads();
        for (int j = wave; j < cn; j += 4) {
            int e = eidx[j];
            const short* kr = kvb + (size_t)e * 512;
            float d0 = warp_sum64(q0 * bf2f(kr[lane]));
            float d1 = warp_sum64(q1 * bf2f(kr[64 + lane]));
            float d2 = warp_sum64(q2 * bf2f(kr[128 + lane]));
            float d3 = warp_sum64(q3 * bf2f(kr[192 + lane]));
            if (lane == 0) {
                scl[j]       = d0 * 0.125f;   // 1/sqrt(64)
                scl[64 + j]  = d1 * 0.125f;
                scl[128 + j] = d2 * 0.125f;
                scl[192 + j] = d3 * 0.125f;
            }
        }
        __syncthreads();
        float s = (lane < cn) ? scl[wave * 64 + lane] : -INFINITY;
        float mc = warp_max64(s);
        float nm = fmaxf(m, mc);
        float scale = __expf(m - nm);
        float pp = (lane < cn) ? __expf(s - nm) : 0.f;
        float ps = warp_sum64(pp);
        l = l * scale + ps;
        out *= scale;
        m = nm;
        for (int i = 0; i < cn; i++) {
            float pi = __shfl(pp, i, 64);
            int ei = eidx[i];
            out += pi * bf2f(kvb[(size_t)ei * 512 + 256 + wave * 64 + lane]);
        }
        __syncthreads();   // protect eidx/scl before next chunk
    }
    float res;
    if (s1 > s0) res = out / l;
    else         res = vbar[wave * 64 + lane] * (1.f / (float)E);  // uniform over all E
    g_bf[(size_t)n * CH + wave * 64 + lane] = f2bf(res);
}

// ==================================================================== launch
extern "C" void kernel_launch(void* const* d_in, const int* in_sizes, int n_in,
                              void* d_out, int out_size, void* d_ws, size_t ws_size,
                              hipStream_t stream)
{
    const float* x       = (const float*)d_in[0];
    const int*   ei      = (const int*)d_in[1];
    const float* eattr   = (const float*)d_in[2];
    const float* gn_e1_g = (const float*)d_in[3];
    const float* gn_e1_b = (const float*)d_in[4];
    const float* We1     = (const float*)d_in[5];
    const float* be1     = (const float*)d_in[6];
    const float* gn_e2_g = (const float*)d_in[7];
    const float* gn_e2_b = (const float*)d_in[8];
    const float* We2     = (const float*)d_in[9];
    const float* be2     = (const float*)d_in[10];
    const float* gn_n_g  = (const float*)d_in[11];
    const float* gn_n_b  = (const float*)d_in[12];
    const float* Wq      = (const float*)d_in[13];
    const float* bq      = (const float*)d_in[14];
    const float* Wk      = (const float*)d_in[15];
    const float* bk      = (const float*)d_in[16];
    const float* Wv      = (const float*)d_in[17];
    const float* bv      = (const float*)d_in[18];
    const float* Wo      = (const float*)d_in[19];
    const float* bo      = (const float*)d_in[20];
    const float* Wn1     = (const float*)d_in[21];
    const float* bn1     = (const float*)d_in[22];
    const float* gn_n2_g = (const float*)d_in[23];
    const float* gn_n2_b = (const float*)d_in[24];
    const float* Wn2     = (const float*)d_in[25];
    const float* bn2     = (const float*)d_in[26];

    const int N = in_sizes[0] / CH;
    const int E = in_sizes[2] / CH;

    float* nout = (float*)d_out;
    float* eout = (float*)d_out + (size_t)N * CH;

    // ---- workspace ----
    char* base = (char*)d_ws;
    short* kv_bf  = (short*)base; base += (size_t)E * 512 * 2;
    short* h2_bf  = (short*)base; base += (size_t)E * CH * 2;
    short* eo_bf  = (short*)base; base += (size_t)E * CH * 2;
    short* eabf   = (short*)base; base += (size_t)E * CH * 2;
    short* q_bf   = (short*)base; base += (size_t)N * CH * 2;
    short* g_bf   = (short*)base; base += (size_t)N * CH * 2;
    short* cat_bf = (short*)base; base += (size_t)N * 2 * CH * 2;
    short* hn_bf  = (short*)base; base += (size_t)N * CH * 2;
    short* x_bf   = (short*)base; base += (size_t)N * CH * 2;
    float2* xs    = (float2*)base; base += (size_t)N * 32 * 8;
    float* mub    = (float*)base; base += (size_t)E * 32 * 4;
    float* rsb    = (float*)base; base += (size_t)E * 32 * 4;
    float* vbar   = (float*)base; base += 1024;
    float* bkv    = (float*)base; base += 2048;
    short* We1t = (short*)base; base += (size_t)768 * 256 * 2;
    short* We2t = (short*)base; base += (size_t)256 * 256 * 2;
    short* Wqt  = (short*)base; base += (size_t)256 * 256 * 2;
    short* Wkvt = (short*)base; base += (size_t)512 * 256 * 2;
    short* Wot  = (short*)base; base += (size_t)256 * 256 * 2;
    short* Wn1t = (short*)base; base += (size_t)512 * 256 * 2;
    short* Wn2t = (short*)base; base += (size_t)256 * 256 * 2;
    int* counts  = (int*)base;
    int* offsets = counts + N;
    int* cursor  = offsets + (N + 1) + 3;
    int* elist   = cursor + N;

    const int* rowi = ei;
    const int* coli = ei + E;

    dim3 blk(256);

    // ---- merged prep ----
    PrepPack pp;
    const float* wsrc[8] = {We1, We2, Wq, Wk, Wv, Wo, Wn1, Wn2};
    short* wdst[8] = {We1t, We2t, Wqt, Wkvt, Wkvt + (size_t)256 * 256, Wot, Wn1t, Wn2t};
    const int wKd[8] = {768, 256, 256, 256, 256, 256, 512, 256};
    int acc = 0;
    for (int i = 0; i < 8; i++) {
        pp.wsrc[i] = wsrc[i]; pp.wdst[i] = wdst[i]; pp.wK[i] = wKd[i];
        pp.wstart[i] = acc; acc += wKd[i] / 16;
    }
    pp.NW = acc;
    pp.NP = (N + 7) / 8;
    pp.x = x; pp.x_bf = x_bf; pp.cat_bf = cat_bf; pp.xs = xs;
    pp.gng = gn_n_g; pp.gnb = gn_n_b;
    pp.vbar = vbar; pp.bk = bk; pp.bv = bv; pp.bkv = bkv;
    pp.counts = counts; pp.N = N;
    int nzero = (N + 255) / 256;
    prep_kernel<<<pp.NW + pp.NP + nzero, blk, 0, stream>>>(pp);

    estats_kernel<<<E / 8, blk, 0, stream>>>(eattr, rowi, coli, xs, mub, rsb,
                                             eabf, counts, E);
    scan_kernel<<<1, 1024, 0, stream>>>(counts, offsets, cursor, N);

    GArgs ga = {};
    // ---- GEMM1: virtual A (bf16 gathers), 64x64, grid (4, 250) ----
    ga.Bt = We1t; ga.bias = be1; ga.Cbf = h2_bf;
    ga.gamma = gn_e2_g; ga.beta = gn_e2_b;
    ga.M = E; ga.K = 3 * CH; ga.Nc = CH; ga.ldc = CH; ga.coff = 0;
    ga.xbf = x_bf; ga.eabf = eabf; ga.rowi = rowi; ga.coli = coli;
    ga.mu = mub; ga.rs = rsb; ga.vg = gn_e1_g; ga.vbt = gn_e1_b;
    mfma_gemm<64, 64, 1, 1, 0, 0, 0><<<dim3(4, E / 64), blk, 0, stream>>>(ga);

    // ---- GEMM2: eout (f32, +eattr residual) + eo_bf ----
    ga = {};
    ga.A = h2_bf; ga.Bt = We2t; ga.bias = be2; ga.res = eattr;
    ga.C = eout; ga.Cbf = eo_bf;
    ga.M = E; ga.K = CH; ga.Nc = CH; ga.ldc = CH; ga.coff = 0;
    mfma_gemm<64, 64, 0, 0, 0, 0, 0><<<dim3(4, E / 64), blk, 0, stream>>>(ga);

    // ---- fused KV (bf16, vbar, CSR fill) + Q (bf16) in one launch ----
    ga = {};
    ga.A = eo_bf; ga.Bt = Wkvt; ga.bias = bkv; ga.Cbf = kv_bf; ga.vbar = vbar;
    ga.M = E; ga.K = CH; ga.Nc = 512; ga.ldc = 512; ga.coff = 0;
    ga.A2 = x_bf; ga.Bt2 = Wqt; ga.bias2 = bq; ga.Cbf2 = q_bf;
    ga.M2 = N; ga.Nc2 = CH; ga.y_split = E / 64;
    ga.coli = coli; ga.cursor = cursor; ga.elist = elist;
    mfma_gemm<64, 64, 0, 0, 1, 1, 1><<<dim3(8, E / 64 + (N + 63) / 64), blk, 0, stream>>>(ga);

    // ---- attention (scores fused in) ----
    attn_kernel<<<N, blk, 0, stream>>>(q_bf, kv_bf, offsets, elist, vbar, g_bf, N, E);

    // ---- Wo -> cat right half (bf16) ----
    ga = {};
    ga.A = g_bf; ga.Bt = Wot; ga.bias = bo; ga.Cbf = cat_bf;
    ga.M = N; ga.K = CH; ga.Nc = CH; ga.ldc = 2 * CH; ga.coff = CH;
    mfma_gemm<32, 64, 0, 0, 0, 0, 0><<<dim3(4, (N + 31) / 32), blk, 0, stream>>>(ga);

    // ---- node MLP ----
    ga = {};
    ga.A = cat_bf; ga.Bt = Wn1t; ga.bias = bn1; ga.Cbf = hn_bf;
    ga.gamma = gn_n2_g; ga.beta = gn_n2_b;
    ga.M = N; ga.K = 2 * CH; ga.Nc = CH; ga.ldc = CH; ga.coff = 0;
    mfma_gemm<32, 64, 0, 1, 0, 0, 0><<<dim3(4, (N + 31) / 32), blk, 0, stream>>>(ga);

    ga = {};
    ga.A = hn_bf; ga.Bt = Wn2t; ga.bias = bn2; ga.res = x; ga.C = nout;
    ga.M = N; ga.K = CH; ga.Nc = CH; ga.ldc = CH; ga.coff = 0;
    mfma_gemm<32, 64, 0, 0, 0, 0, 0><<<dim3(4, (N + 31) / 32), blk, 0, stream>>>(ga);
}